// Round 1
// baseline (214.672 us; speedup 1.0000x reference)
//
#include <hip/hip_runtime.h>
#include <stdint.h>

#define HID 512
#define NH 8
#define HD 64
#define BB 4
#define SS 2048

typedef unsigned short u16;
typedef __attribute__((ext_vector_type(8))) short short8;
typedef __attribute__((ext_vector_type(4))) float f32x4;

#define MFMA16(a, b, c) __builtin_amdgcn_mfma_f32_16x16x32_bf16((a), (b), (c), 0, 0, 0)

__device__ __forceinline__ u16 f2bf(float f) {
  union { float f; uint32_t u; } v; v.f = f;
  return (u16)((v.u + 0x7fffu + ((v.u >> 16) & 1u)) >> 16);
}

__device__ __forceinline__ void gl_lds16(const u16* g, u16* l) {
  __builtin_amdgcn_global_load_lds(
      (const __attribute__((address_space(1))) unsigned int*)g,
      (__attribute__((address_space(3))) unsigned int*)l, 16, 0, 0);
}

// ---------------------------------------------------------------- convert
__global__ void cvt_f32_bf16(const float* __restrict__ in, u16* __restrict__ out, int n) {
  int i = (blockIdx.x * blockDim.x + threadIdx.x) * 4;
  if (i >= n) return;
  float4 v = *(const float4*)(in + i);
  ushort4 o;
  o.x = f2bf(v.x); o.y = f2bf(v.y); o.z = f2bf(v.z); o.w = f2bf(v.w);
  *(ushort4*)(out + i) = o;
}

// ---------------------------------------------------------------- QKV GEMM
// out[r,o] = sum_k xb[r,k] * W[o,k] (+bias). 128x128 tile, BK=32, 4 waves 2x2.
// z=0 -> Q (scaled 1/8, layout [B,H,S,D]); z=1 -> K ([B,H,S,D]); z=2 -> V^T ([B,H,D,S])
__global__ __launch_bounds__(256, 3)
void qkv_gemm(const u16* __restrict__ xb,
              const u16* __restrict__ wq, const u16* __restrict__ wk, const u16* __restrict__ wv,
              const float* __restrict__ bq, const float* __restrict__ bk, const float* __restrict__ bv,
              u16* __restrict__ Q, u16* __restrict__ K, u16* __restrict__ Vt) {
  __shared__ u16 sA[128 * 32];
  __shared__ u16 sB[128 * 32];
  const int tid = threadIdx.x;
  const int lane = tid & 63;
  const int wave = tid >> 6;
  const int l15 = lane & 15;
  const int quad = lane >> 4;
  const int wm = wave >> 1, wn = wave & 1;
  const int bm = blockIdx.x, bn = blockIdx.y, z = blockIdx.z;

  const u16* W = (z == 0) ? wq : (z == 1) ? wk : wv;
  const float* bias = (z == 0) ? bq : (z == 1) ? bk : bv;

  // staging: granule G = it*256+tid; row=G>>2, stored g = orig_g ^ ((row>>1)&3)
  const int srow = tid >> 2;
  const int sg = (tid & 3) ^ ((srow >> 1) & 3);
  const u16* gA = xb + (bm * 128 + srow) * 512 + sg * 8;
  const u16* gB = W + (bn * 128 + srow) * 512 + sg * 8;

  // fragment LDS offsets (constant across k-iters; swizzle: g' = quad ^ ((l15>>1)&3))
  const int fsw = (quad ^ ((l15 >> 1) & 3)) * 8;
  int aoff[4], boff[4];
#pragma unroll
  for (int t = 0; t < 4; ++t) {
    aoff[t] = (wm * 64 + t * 16 + l15) * 32 + fsw;
    boff[t] = (wn * 64 + t * 16 + l15) * 32 + fsw;
  }

  f32x4 acc[4][4] = {};

  for (int kk = 0; kk < 16; ++kk) {
    const int k0 = kk * 32;
    gl_lds16(gA + k0, &sA[wave * 512]);
    gl_lds16(gA + k0 + 64 * 512, &sA[2048 + wave * 512]);
    gl_lds16(gB + k0, &sB[wave * 512]);
    gl_lds16(gB + k0 + 64 * 512, &sB[2048 + wave * 512]);
    __syncthreads();
    short8 af[4], bf[4];
#pragma unroll
    for (int t = 0; t < 4; ++t) af[t] = *(const short8*)&sA[aoff[t]];
#pragma unroll
    for (int t = 0; t < 4; ++t) bf[t] = *(const short8*)&sB[boff[t]];
#pragma unroll
    for (int mi = 0; mi < 4; ++mi)
#pragma unroll
      for (int ni = 0; ni < 4; ++ni)
        acc[mi][ni] = MFMA16(af[mi], bf[ni], acc[mi][ni]);
    __syncthreads();
  }

#pragma unroll
  for (int mi = 0; mi < 4; ++mi) {
#pragma unroll
    for (int ni = 0; ni < 4; ++ni) {
      const int col = bn * 128 + wn * 64 + ni * 16 + l15;
      const float bs = bias[col];
#pragma unroll
      for (int i = 0; i < 4; ++i) {
        const int row = bm * 128 + wm * 64 + mi * 16 + quad * 4 + i;
        const float v = acc[mi][ni][i] + bs;
        const int b = row >> 11, s = row & 2047;
        const int h = col >> 6, d = col & 63;
        if (z == 0) {
          Q[(((size_t)(b * 8 + h) * 2048 + s) << 6) + d] = f2bf(v * 0.125f);
        } else if (z == 1) {
          K[(((size_t)(b * 8 + h) * 2048 + s) << 6) + d] = f2bf(v);
        } else {
          Vt[(((size_t)(b * 8 + h) * 64 + d) << 11) + s] = f2bf(v);
        }
      }
    }
  }
}

// ---------------------------------------------------------------- attention
// one block = 128 Q-rows of one (b,h). 4 waves x 32 rows. Online softmax.
__global__ __launch_bounds__(256, 2)
void attn(const u16* __restrict__ Q, const u16* __restrict__ K,
          const u16* __restrict__ Vt, u16* __restrict__ ctx) {
  __shared__ u16 sK[128 * 64];   // [t][d], d-granules swizzled ^ (t&7)
  __shared__ u16 sV[64 * 128];   // [d][t], t-granules swizzled ^ (d&15)
  __shared__ u16 sP[128 * 128];  // [r][t], t-granules swizzled ^ (r&15)
  const int tid = threadIdx.x;
  const int lane = tid & 63;
  const int wave = tid >> 6;
  const int l15 = lane & 15;
  const int quad = lane >> 4;
  const int qt = blockIdx.x;  // 0..15
  const int bh = blockIdx.y;  // 0..31

  const u16* Qb = Q + (size_t)bh * SS * HD;
  const u16* Kb = K + (size_t)bh * SS * HD;
  const u16* Vb = Vt + (size_t)bh * HD * SS;

  // Q fragments (A-layout, direct from global; Q pre-scaled by 1/8)
  short8 qf[2][2];
#pragma unroll
  for (int mi = 0; mi < 2; ++mi)
#pragma unroll
    for (int kc = 0; kc < 2; ++kc) {
      const int r = qt * 128 + wave * 32 + mi * 16 + l15;
      qf[mi][kc] = *(const short8*)(Qb + r * 64 + kc * 32 + quad * 8);
    }

  f32x4 oacc[2][4] = {};
  float mrow[2][4], lrow[2][4];
#pragma unroll
  for (int mi = 0; mi < 2; ++mi)
#pragma unroll
    for (int i = 0; i < 4; ++i) { mrow[mi][i] = -1e30f; lrow[mi][i] = 0.f; }

  // staging source addresses
  const int tK = tid >> 3;
  const int dcK = (tid & 7) ^ (tK & 7);
  const u16* gK = Kb + tK * 64 + dcK * 8;
  const int dV = tid >> 4;
  const int tgV = (tid & 15) ^ dV;
  const u16* gV = Vb + dV * 2048 + tgV * 8;

  // fragment LDS offsets
  int koffB[2];
  koffB[0] = l15 * 64 + ((quad) ^ (l15 & 7)) * 8;
  koffB[1] = l15 * 64 + ((4 + quad) ^ (l15 & 7)) * 8;
  int xq[4];
#pragma unroll
  for (int kt = 0; kt < 4; ++kt) xq[kt] = ((kt * 4 + quad) ^ l15) * 8;

  for (int tt = 0; tt < 16; ++tt) {
#pragma unroll
    for (int it = 0; it < 4; ++it)
      gl_lds16(gK + tt * 8192 + it * 2048, &sK[it * 2048 + wave * 512]);
#pragma unroll
    for (int it = 0; it < 4; ++it)
      gl_lds16(gV + tt * 128 + it * 32768, &sV[it * 2048 + wave * 512]);
    __syncthreads();

    // scores S = Q K^T (scale folded into Q)
    f32x4 sacc[2][8] = {};
#pragma unroll
    for (int ni = 0; ni < 8; ++ni) {
      const short8 b0 = *(const short8*)&sK[ni * 1024 + koffB[0]];
      const short8 b1 = *(const short8*)&sK[ni * 1024 + koffB[1]];
#pragma unroll
      for (int mi = 0; mi < 2; ++mi) {
        sacc[mi][ni] = MFMA16(qf[mi][0], b0, sacc[mi][ni]);
        sacc[mi][ni] = MFMA16(qf[mi][1], b1, sacc[mi][ni]);
      }
    }

    // online softmax per row; write P (bf16) into swizzled LDS
#pragma unroll
    for (int mi = 0; mi < 2; ++mi) {
#pragma unroll
      for (int i = 0; i < 4; ++i) {
        float mx = sacc[mi][0][i];
#pragma unroll
        for (int ni = 1; ni < 8; ++ni) mx = fmaxf(mx, sacc[mi][ni][i]);
#pragma unroll
        for (int off = 1; off < 16; off <<= 1) mx = fmaxf(mx, __shfl_xor(mx, off, 16));
        const float mnew = fmaxf(mrow[mi][i], mx);
        const float alpha = __expf(mrow[mi][i] - mnew);
        mrow[mi][i] = mnew;
        float rs = 0.f;
#pragma unroll
        for (int ni = 0; ni < 8; ++ni) {
          const float p = __expf(sacc[mi][ni][i] - mnew);
          sacc[mi][ni][i] = p;
          rs += p;
        }
#pragma unroll
        for (int off = 1; off < 16; off <<= 1) rs += __shfl_xor(rs, off, 16);
        lrow[mi][i] = lrow[mi][i] * alpha + rs;
#pragma unroll
        for (int nd = 0; nd < 4; ++nd) oacc[mi][nd][i] *= alpha;
        const int wrow = wave * 32 + mi * 16 + quad * 4 + i;
        const int rx = wrow & 15;
        const int base = wrow * 128 + (l15 & 7);
#pragma unroll
        for (int ni = 0; ni < 8; ++ni) {
          const int g2 = (ni * 2 + (l15 >> 3)) ^ rx;
          sP[base + g2 * 8] = f2bf(sacc[mi][ni][i]);
        }
      }
    }

    // ctx += P V   (each wave reads only its own 32 P-rows -> no barrier needed)
#pragma unroll
    for (int kt = 0; kt < 4; ++kt) {
      const short8 a0 = *(const short8*)&sP[(wave * 32 + l15) * 128 + xq[kt]];
      const short8 a1 = *(const short8*)&sP[(wave * 32 + 16 + l15) * 128 + xq[kt]];
#pragma unroll
      for (int nd = 0; nd < 4; ++nd) {
        const short8 bvv = *(const short8*)&sV[(nd * 16 + l15) * 128 + xq[kt]];
        oacc[0][nd] = MFMA16(a0, bvv, oacc[0][nd]);
        oacc[1][nd] = MFMA16(a1, bvv, oacc[1][nd]);
      }
    }
    __syncthreads();
  }

  const int b = bh >> 3, h = bh & 7;
#pragma unroll
  for (int mi = 0; mi < 2; ++mi)
#pragma unroll
    for (int nd = 0; nd < 4; ++nd)
#pragma unroll
      for (int i = 0; i < 4; ++i) {
        const int s = qt * 128 + wave * 32 + mi * 16 + quad * 4 + i;
        const int d = nd * 16 + l15;
        const float v = oacc[mi][nd][i] / lrow[mi][i];
        ctx[((size_t)(b * 2048 + s) << 9) + h * 64 + d] = f2bf(v);
      }
}

// ---------------------------------------------------------------- out GEMM
__global__ __launch_bounds__(256, 3)
void out_gemm(const u16* __restrict__ A, const u16* __restrict__ W,
              const float* __restrict__ bias, float* __restrict__ out) {
  __shared__ u16 sA[128 * 32];
  __shared__ u16 sB[128 * 32];
  const int tid = threadIdx.x;
  const int lane = tid & 63;
  const int wave = tid >> 6;
  const int l15 = lane & 15;
  const int quad = lane >> 4;
  const int wm = wave >> 1, wn = wave & 1;
  const int bm = blockIdx.x, bn = blockIdx.y;

  const int srow = tid >> 2;
  const int sg = (tid & 3) ^ ((srow >> 1) & 3);
  const u16* gA = A + (bm * 128 + srow) * 512 + sg * 8;
  const u16* gB = W + (bn * 128 + srow) * 512 + sg * 8;

  const int fsw = (quad ^ ((l15 >> 1) & 3)) * 8;
  int aoff[4], boff[4];
#pragma unroll
  for (int t = 0; t < 4; ++t) {
    aoff[t] = (wm * 64 + t * 16 + l15) * 32 + fsw;
    boff[t] = (wn * 64 + t * 16 + l15) * 32 + fsw;
  }

  f32x4 acc[4][4] = {};

  for (int kk = 0; kk < 16; ++kk) {
    const int k0 = kk * 32;
    gl_lds16(gA + k0, &sA[wave * 512]);
    gl_lds16(gA + k0 + 64 * 512, &sA[2048 + wave * 512]);
    gl_lds16(gB + k0, &sB[wave * 512]);
    gl_lds16(gB + k0 + 64 * 512, &sB[2048 + wave * 512]);
    __syncthreads();
    short8 af[4], bf[4];
#pragma unroll
    for (int t = 0; t < 4; ++t) af[t] = *(const short8*)&sA[aoff[t]];
#pragma unroll
    for (int t = 0; t < 4; ++t) bf[t] = *(const short8*)&sB[boff[t]];
#pragma unroll
    for (int mi = 0; mi < 4; ++mi)
#pragma unroll
      for (int ni = 0; ni < 4; ++ni)
        acc[mi][ni] = MFMA16(af[mi], bf[ni], acc[mi][ni]);
    __syncthreads();
  }

#pragma unroll
  for (int mi = 0; mi < 4; ++mi) {
#pragma unroll
    for (int ni = 0; ni < 4; ++ni) {
      const int col = bn * 128 + wn * 64 + ni * 16 + l15;
      const float bs = bias[col];
#pragma unroll
      for (int i = 0; i < 4; ++i) {
        const int row = bm * 128 + wm * 64 + mi * 16 + quad * 4 + i;
        out[(size_t)row * 512 + col] = acc[mi][ni][i] + bs;
      }
    }
  }
}

// ---------------------------------------------------------------- launch
extern "C" void kernel_launch(void* const* d_in, const int* in_sizes, int n_in,
                              void* d_out, int out_size, void* d_ws, size_t ws_size,
                              hipStream_t stream) {
  const float* x = (const float*)d_in[0];
  const float* Wq = (const float*)d_in[1];
  const float* bq = (const float*)d_in[2];
  const float* Wk = (const float*)d_in[3];
  const float* bk = (const float*)d_in[4];
  const float* Wv = (const float*)d_in[5];
  const float* bv = (const float*)d_in[6];
  const float* Wo = (const float*)d_in[7];
  const float* bo = (const float*)d_in[8];
  float* out = (float*)d_out;

  char* ws = (char*)d_ws;
  u16* xb  = (u16*)(ws);                    // 8 MiB
  u16* wqb = (u16*)(ws + 8388608);          // 512 KiB
  u16* wkb = (u16*)(ws + 8912896);
  u16* wvb = (u16*)(ws + 9437184);
  u16* wob = (u16*)(ws + 9961472);
  u16* Qb  = (u16*)(ws + 10485760);         // 8 MiB  [B,H,S,D], pre-scaled 1/8
  u16* Kb  = (u16*)(ws + 18874368);         // 8 MiB  [B,H,S,D]
  u16* Vtb = (u16*)(ws + 27262976);         // 8 MiB  [B,H,D,S]
  u16* ctx = (u16*)(ws + 35651584);         // 8 MiB  [B,S,HID]

  cvt_f32_bf16<<<4096, 256, 0, stream>>>(x, xb, BB * SS * HID);
  cvt_f32_bf16<<<256, 256, 0, stream>>>(Wq, wqb, HID * HID);
  cvt_f32_bf16<<<256, 256, 0, stream>>>(Wk, wkb, HID * HID);
  cvt_f32_bf16<<<256, 256, 0, stream>>>(Wv, wvb, HID * HID);
  cvt_f32_bf16<<<256, 256, 0, stream>>>(Wo, wob, HID * HID);

  qkv_gemm<<<dim3(64, 4, 3), 256, 0, stream>>>(xb, wqb, wkb, wvb, bq, bk, bv, Qb, Kb, Vtb);
  attn<<<dim3(16, 32), 256, 0, stream>>>(Qb, Kb, Vtb, ctx);
  out_gemm<<<dim3(64, 4), 256, 0, stream>>>(ctx, wob, bo, out);
}